// Round 12
// baseline (57.467 us; speedup 1.0000x reference)
//
#include <hip/hip_runtime.h>
#include <hip/hip_bf16.h>
#include <cmath>

#define BATCH 2
#define LSEQ 2048
#define DMODEL 512
#define NHEADS 8
#define HD 64
#define RATIO 8
#define STRIDE 4
#define WINDOW 128
#define LC 511   // (2048-8)/4 + 1

typedef short short8 __attribute__((ext_vector_type(8)));
typedef float floatx4 __attribute__((ext_vector_type(4)));
typedef float floatx16 __attribute__((ext_vector_type(16)));

__device__ inline unsigned short f2bf(float f) {
  unsigned u = __float_as_uint(f);
  u += 0x7FFFu + ((u >> 16) & 1u);
  return (unsigned short)(u >> 16);
}

// async global->LDS 16B (dwordx4). LDS dest is wave-uniform base + lane*16.
__device__ inline void gld_lds16(const unsigned short* g, short* l) {
  __builtin_amdgcn_global_load_lds(
      (const __attribute__((address_space(1))) unsigned int*)g,
      (__attribute__((address_space(3))) unsigned int*)l, 16, 0, 0);
}

// ---------------------------------------------------------------------------
// Fused elementwise pass:
//   [0, 524288)           : x -> xb (bf16)
//   [524288, 917504)      : 6 weights -> wqkvb/wkvcb/wob (bf16)
//   [917504, 1048320)     : xc build (fp32 x -> bf16 xcb)
//   [1048320, 1113856)    : RoPE cos/sin table (float2 cstab[2048*32])
// ---------------------------------------------------------------------------
__global__ void conv_all(const float* __restrict__ x,
                         const float* __restrict__ w0, const float* __restrict__ w1,
                         const float* __restrict__ w2, const float* __restrict__ w3,
                         const float* __restrict__ w4, const float* __restrict__ w5,
                         const float* __restrict__ gate,
                         unsigned short* __restrict__ xb,
                         unsigned short* __restrict__ wqkvb,
                         unsigned short* __restrict__ wkvcb,
                         unsigned short* __restrict__ wob,
                         unsigned short* __restrict__ xcb,
                         float2* __restrict__ cstab) {
  int idx = blockIdx.x * blockDim.x + threadIdx.x;
  if (idx < 917504) {
    const float* src;
    unsigned short* dst;
    int off;
    if (idx < 524288) {
      src = x; dst = xb; off = idx;
    } else {
      int r = idx - 524288;
      int wi = r >> 16;
      off = r & 65535;
      switch (wi) {
        case 0: src = w0; dst = wqkvb; break;
        case 1: src = w1; dst = wqkvb + 4 * 65536; break;
        case 2: src = w2; dst = wqkvb + 8 * 65536; break;
        case 3: src = w3; dst = wkvcb; break;
        case 4: src = w4; dst = wkvcb + 4 * 65536; break;
        default: src = w5; dst = wob; break;
      }
    }
    float4 v = ((const float4*)src)[off];
    ushort4 o;
    o.x = f2bf(v.x); o.y = f2bf(v.y); o.z = f2bf(v.z); o.w = f2bf(v.w);
    ((ushort4*)dst)[off] = o;
  } else if (idx < 1048320) {
    int r = idx - 917504;           // [0, 130816) = 1022 * 128
    int d4 = r & 127;
    int t = r >> 7;
    int w = t % LC;
    int b = t / LC;
    float g[8];
    float m = -1e30f;
#pragma unroll
    for (int i = 0; i < 8; ++i) { g[i] = gate[i]; m = fmaxf(m, g[i]); }
    float ssum = 0.f;
#pragma unroll
    for (int i = 0; i < 8; ++i) { g[i] = __expf(g[i] - m); ssum += g[i]; }
    float inv = 1.f / ssum;
    const float* xb4 = x + ((size_t)(b * LSEQ + w * STRIDE)) * DMODEL + d4 * 4;
    float4 acc = make_float4(0.f, 0.f, 0.f, 0.f);
#pragma unroll
    for (int i = 0; i < 8; ++i) {
      float4 v = *(const float4*)(xb4 + (size_t)i * DMODEL);
      acc.x += g[i] * v.x; acc.y += g[i] * v.y;
      acc.z += g[i] * v.z; acc.w += g[i] * v.w;
    }
    ushort4 o;
    o.x = f2bf(acc.x * inv); o.y = f2bf(acc.y * inv);
    o.z = f2bf(acc.z * inv); o.w = f2bf(acc.w * inv);
    ((ushort4*)xcb)[(size_t)(b * LC + w) * 128 + d4] = o;
  } else {
    int e = idx - 1048320;          // [0, 65536) = 2048 * 32
    int p = e >> 5, j = e & 31;
    float inv_freq = __expf(-(float)j * (9.210340371976184f / 32.f));
    float s, c;
    sincosf((float)p * inv_freq, &s, &c);
    cstab[e] = make_float2(c, s);
  }
}

// ---------------------------------------------------------------------------
// Fused projection GEMM (448 blocks, 128x128 tiles, BK=64, 2-phase pipeline,
// 32x32x16 MFMA: wave tile 64x64 = 2x2 frags of 32x32, 16 f32 regs each).
// C/D layout: col = lane&31, row = (reg&3) + 8*(reg>>2) + 4*(lane>>5).
// bid<384: QKV (RoPE fused); bid>=384: KCVC (row-clamped A).
// ---------------------------------------------------------------------------
__global__ __launch_bounds__(256) void proj_gemm(
    const unsigned short* __restrict__ xb, const unsigned short* __restrict__ xcb,
    const unsigned short* __restrict__ wqkvb, const unsigned short* __restrict__ wkvcb,
    const float2* __restrict__ cstab,
    unsigned short* __restrict__ qbuf, unsigned short* __restrict__ kbuf,
    unsigned short* __restrict__ vbuf, unsigned short* __restrict__ kcb,
    unsigned short* __restrict__ vcb) {
  __shared__ short As[2][128 * 64];
  __shared__ short Bs[2][128 * 64];
  const int tid = threadIdx.x;
  const int w = tid >> 6, l = tid & 63;
  const int khi = l >> 5;          // k-subgroup of 8 within a 16-chunk
  const int lc = l & 31;           // row-within-frag / output col

  const int bid = blockIdx.x;
  const bool qkv = (bid < 384);
  const unsigned short* Ap;
  const unsigned short* Bp;
  int bm, bn, Am1;
  if (qkv) {
    Ap = xb; Bp = wqkvb; bm = (bid & 31) * 128; bn = (bid >> 5) * 128; Am1 = 4095;
  } else {
    int r = bid - 384;
    Ap = xcb; Bp = wkvcb; bm = (r & 7) * 128; bn = (r >> 3) * 128; Am1 = 1021;
  }
  const int wm = (w >> 1) * 64, wn = (w & 1) * 64;

  floatx16 acc[2][2];
#pragma unroll
  for (int i = 0; i < 2; ++i)
#pragma unroll
    for (int j = 0; j < 2; ++j) acc[i][j] = 0.f;

  const int trow = tid >> 3;
  const int cs = (tid & 7) ^ (trow & 7);
  size_t aoffs[4];
#pragma unroll
  for (int i = 0; i < 4; ++i) {
    int ar = bm + trow + i * 32;
    if (ar > Am1) ar = Am1;
    aoffs[i] = (size_t)ar * DMODEL + cs * 8;
  }
  const size_t boff = (size_t)(bn + trow) * DMODEL + cs * 8;
  const int ldsbase = (tid & 192) * 8;

  auto stage = [&](int ks, int buf) {
    const int k0 = ks * 64;
#pragma unroll
    for (int i = 0; i < 4; ++i) {
      gld_lds16(Ap + aoffs[i] + k0, &As[buf][i * 2048 + ldsbase]);
      gld_lds16(Bp + boff + (size_t)i * 32 * DMODEL + k0, &Bs[buf][i * 2048 + ldsbase]);
    }
  };

  stage(0, 0);
  __syncthreads();
  for (int ks = 0; ks < 8; ++ks) {
    const int cur = ks & 1;
    if (ks < 7) stage(ks + 1, cur ^ 1);
#pragma unroll
    for (int kc = 0; kc < 4; ++kc) {     // 4 k-chunks of 16 per K-step
      const int g = kc * 2 + khi;
      const int ra0 = wm + lc, ra1 = wm + 32 + lc;
      const int rb0 = wn + lc, rb1 = wn + 32 + lc;
      short8 a0 = *(const short8*)&As[cur][ra0 * 64 + ((g ^ (ra0 & 7)) * 8)];
      short8 a1 = *(const short8*)&As[cur][ra1 * 64 + ((g ^ (ra1 & 7)) * 8)];
      short8 b0 = *(const short8*)&Bs[cur][rb0 * 64 + ((g ^ (rb0 & 7)) * 8)];
      short8 b1 = *(const short8*)&Bs[cur][rb1 * 64 + ((g ^ (rb1 & 7)) * 8)];
      acc[0][0] = __builtin_amdgcn_mfma_f32_32x32x16_bf16(a0, b0, acc[0][0], 0, 0, 0);
      acc[0][1] = __builtin_amdgcn_mfma_f32_32x32x16_bf16(a0, b1, acc[0][1], 0, 0, 0);
      acc[1][0] = __builtin_amdgcn_mfma_f32_32x32x16_bf16(a1, b0, acc[1][0], 0, 0, 0);
      acc[1][1] = __builtin_amdgcn_mfma_f32_32x32x16_bf16(a1, b1, acc[1][1], 0, 0, 0);
    }
    __syncthreads();
  }

  if (qkv) {
    if (bn < 1024) {
      // q or k: wave's 64 cols = exactly one head; pair (d, d+32) =
      // (acc[rb][0][reg], acc[rb][1][reg]), j = lc indexes cstab directly.
      unsigned short* dst = (bn < 512) ? qbuf : kbuf;
      const int cbase = (bn + wn) & 511;
#pragma unroll
      for (int rb = 0; rb < 2; ++rb) {
#pragma unroll
        for (int reg = 0; reg < 16; ++reg) {
          int row = bm + wm + rb * 32 + (reg & 3) + 8 * (reg >> 2) + 4 * khi;
          int p = row & 2047;
          float2 cssin = cstab[p * 32 + lc];
          float x1 = acc[rb][0][reg], x2 = acc[rb][1][reg];
          dst[(size_t)row * 512 + cbase + lc]      = f2bf(x1 * cssin.x - x2 * cssin.y);
          dst[(size_t)row * 512 + cbase + lc + 32] = f2bf(x1 * cssin.y + x2 * cssin.x);
        }
      }
    } else {
#pragma unroll
      for (int rb = 0; rb < 2; ++rb) {
#pragma unroll
        for (int reg = 0; reg < 16; ++reg) {
          int row = bm + wm + rb * 32 + (reg & 3) + 8 * (reg >> 2) + 4 * khi;
#pragma unroll
          for (int cb = 0; cb < 2; ++cb) {
            int col = bn + wn + cb * 32 + lc - 1024;
            vbuf[(size_t)row * 512 + col] = f2bf(acc[rb][cb][reg]);
          }
        }
      }
    }
  } else {
    unsigned short* dst = ((bn + wn) < 512) ? kcb : vcb;
    const int cbase = (bn + wn) & 511;
#pragma unroll
    for (int rb = 0; rb < 2; ++rb) {
#pragma unroll
      for (int reg = 0; reg < 16; ++reg) {
        int row = bm + wm + rb * 32 + (reg & 3) + 8 * (reg >> 2) + 4 * khi;
        if (row < 1022) {
#pragma unroll
          for (int cb = 0; cb < 2; ++cb)
            dst[(size_t)row * 512 + cbase + cb * 32 + lc] = f2bf(acc[rb][cb][reg]);
        }
      }
    }
  }
}

// ---------------------------------------------------------------------------
// Output projection: C[4096,512] = ob x wob^T, fp32 out. 128x64 tiles,
// 2-phase pipelined staging, 32x32x16 MFMA (wave tile 64x32).
// ---------------------------------------------------------------------------
__global__ __launch_bounds__(256) void wo_gemm(
    const unsigned short* __restrict__ A, const unsigned short* __restrict__ B,
    float* __restrict__ C) {
  __shared__ short As[2][128 * 64];
  __shared__ short Bs[2][64 * 64];
  const int tid = threadIdx.x;
  const int w = tid >> 6, l = tid & 63;
  const int khi = l >> 5, lc = l & 31;
  const int bm = blockIdx.x * 128, bn = blockIdx.y * 64;
  const int wm = (w >> 1) * 64, wn = (w & 1) * 32;

  floatx16 acc[2];
  acc[0] = 0.f; acc[1] = 0.f;

  const int trow = tid >> 3;
  const int cs = (tid & 7) ^ (trow & 7);
  const size_t aoff = (size_t)(bm + trow) * DMODEL + cs * 8;
  const size_t boff = (size_t)(bn + trow) * DMODEL + cs * 8;
  const int ldsbase = (tid & 192) * 8;

  auto stage = [&](int ks, int buf) {
    const int k0 = ks * 64;
#pragma unroll
    for (int i = 0; i < 4; ++i)
      gld_lds16(A + aoff + (size_t)i * 32 * DMODEL + k0, &As[buf][i * 2048 + ldsbase]);
#pragma unroll
    for (int i = 0; i < 2; ++i)
      gld_lds16(B + boff + (size_t)i * 32 * DMODEL + k0, &Bs[buf][i * 2048 + ldsbase]);
  };

  stage(0, 0);
  __syncthreads();
  for (int ks = 0; ks < 8; ++ks) {
    const int cur = ks & 1;
    if (ks < 7) stage(ks + 1, cur ^ 1);
#pragma unroll
    for (int kc = 0; kc < 4; ++kc) {
      const int g = kc * 2 + khi;
      const int ra0 = wm + lc, ra1 = wm + 32 + lc;
      const int rb0 = wn + lc;
      short8 a0 = *(const short8*)&As[cur][ra0 * 64 + ((g ^ (ra0 & 7)) * 8)];
      short8 a1 = *(const short8*)&As[cur][ra1 * 64 + ((g ^ (ra1 & 7)) * 8)];
      short8 b0 = *(const short8*)&Bs[cur][rb0 * 64 + ((g ^ (rb0 & 7)) * 8)];
      acc[0] = __builtin_amdgcn_mfma_f32_32x32x16_bf16(a0, b0, acc[0], 0, 0, 0);
      acc[1] = __builtin_amdgcn_mfma_f32_32x32x16_bf16(a1, b0, acc[1], 0, 0, 0);
    }
    __syncthreads();
  }

#pragma unroll
  for (int rb = 0; rb < 2; ++rb) {
#pragma unroll
    for (int reg = 0; reg < 16; ++reg) {
      int row = bm + wm + rb * 32 + (reg & 3) + 8 * (reg >> 2) + 4 * khi;
      C[(size_t)row * 512 + bn + wn + lc] = acc[rb][reg];
    }
  }
}

// ---------------------------------------------------------------------------
// Attention v8 (unchanged): swapped-QK in-lane softmax + wave-uniform mask
// fast paths + double-buffered staging + setprio around MFMA clusters.
// ---------------------------------------------------------------------------
__global__ __launch_bounds__(256, 2) void attn_kernel(
    const unsigned short* __restrict__ qb, const unsigned short* __restrict__ kb,
    const unsigned short* __restrict__ vb, const unsigned short* __restrict__ kcb,
    const unsigned short* __restrict__ vcb, const float* __restrict__ sink,
    unsigned short* __restrict__ ob) {
  __shared__ short Ks[2][64][72];
  __shared__ short Vt[2][64][72];
  __shared__ short Pl[4][16][72];

  const int n = blockIdx.x;
  const int b = n >> 8;
  const int mm = n & 255;
  const int h = mm >> 5;
  int qt = mm & 31;
  if (b) qt = 31 - qt;
  const int q0 = qt * 64;
  const int tid = threadIdx.x;
  const int w = tid >> 6, l = tid & 63;
  const int lr = l & 15, lg = l >> 4;
  const int hoff = h * HD;

  short8 Qa0, Qa1;
  {
    const unsigned short* qrow =
        qb + ((size_t)(b * LSEQ + q0 + w * 16 + lr)) * DMODEL + hoff;
    Qa0 = *(const short8*)(qrow + lg * 8);
    Qa1 = *(const short8*)(qrow + 32 + lg * 8);
  }

  floatx4 Oacc[4];
#pragma unroll
  for (int f = 0; f < 4; ++f) Oacc[f] = 0.f;
  float mrow = -3.0e38f, lrow = 0.f;    // per-lane: q = q0 + w*16 + lr

  int ncm = q0 / 4 + 15;
  if (ncm > LC) ncm = LC;
  const int ntc = (ncm + 63) >> 6;
  const int w0 = (q0 > 127) ? (q0 - 127) : 0;
  const int ntw = (q0 + 64 - w0 + 63) >> 6;
  const int ntt = ntc + ntw;

  const int skey = tid >> 2, sd = (tid & 3) * 16;
  const int vkey = (tid & 31) * 2, vd = (tid >> 5) * 8;
  const int p = q0 + w * 16 + lr;       // lane-fixed query position
  const int pmin = q0 + w * 16;         // wave-uniform min query

  short8 kreg0, kreg1, vreg0, vreg1;

  auto load_tile = [&](int tt) {
    const bool isC = (tt < ntc);
    const int tbase = isC ? tt * 64 : (w0 + (tt - ntc) * 64);
    const unsigned short* Kp = isC ? kcb : kb;
    const unsigned short* Vp = isC ? vcb : vb;
    const int rmax = isC ? (LC - 1) : (LSEQ - 1);
    const size_t brow = isC ? (size_t)(b * LC) : (size_t)(b * LSEQ);
    int kr = tbase + skey;      if (kr > rmax) kr = rmax;
    int vr0 = tbase + vkey;     if (vr0 > rmax) vr0 = rmax;
    int vr1 = tbase + vkey + 1; if (vr1 > rmax) vr1 = rmax;
    const unsigned short* src = Kp + (brow + kr) * DMODEL + hoff + sd;
    kreg0 = *(const short8*)(src);
    kreg1 = *(const short8*)(src + 8);
    vreg0 = *(const short8*)(Vp + (brow + vr0) * DMODEL + hoff + vd);
    vreg1 = *(const short8*)(Vp + (brow + vr1) * DMODEL + hoff + vd);
  };
  auto store_tile = [&](int bsel) {
    *(short8*)&Ks[bsel][skey][sd] = kreg0;
    *(short8*)&Ks[bsel][skey][sd + 8] = kreg1;
#pragma unroll
    for (int j = 0; j < 8; ++j) {
      unsigned pk = (unsigned)(unsigned short)vreg0[j] |
                    ((unsigned)(unsigned short)vreg1[j] << 16);
      *(unsigned*)&Vt[bsel][vd + j][vkey] = pk;
    }
  };

  load_tile(0);

  for (int tt = 0; tt < ntt; ++tt) {
    const int bsel = tt & 1;
    store_tile(bsel);
    if (tt + 1 < ntt) load_tile(tt + 1);
    __syncthreads();

    const bool isC = (tt < ntc);
    const int tbase = isC ? tt * 64 : (w0 + (tt - ntc) * 64);

    // wave-uniform classification
    const bool deadTile = isC ? (tbase * 4 + 7 > pmin + 15)     // all keys future
                              : (tbase > pmin + 15);
    if (deadTile) continue;   // staging/barrier already done; skip compute
    const bool fullTile = isC
        ? ((tbase + 63) * 4 + 7 <= pmin) && (tbase + 63 <= LC - 1)
        : (tbase + 63 <= pmin) && (tbase >= pmin + 15 - (WINDOW - 1));

    // ---- S = K Q^T (swapped): lane q=lr fixed, keys = tbase+f*16+lg*4+i ----
    floatx4 S4[4];
    __builtin_amdgcn_s_setprio(1);
#pragma unroll
    for (int f = 0; f < 4; ++f) {
      floatx4 acc = 0.f;
      short8 kf0 = *(const short8*)&Ks[bsel][f * 16 + lr][lg * 8];
      short8 kf1 = *(const short8*)&Ks[bsel][f * 16 + lr][32 + lg * 8];
      acc = __builtin_amdgcn_mfma_f32_16x16x32_bf16(kf0, Qa0, acc, 0, 0, 0);
      acc = __builtin_amdgcn_mfma_f32_16x16x32_bf16(kf1, Qa1, acc, 0, 0, 0);
      S4[f] = acc;
    }
    __builtin_amdgcn_s_setprio(0);

    // ---- mask + scale; in-lane row max ----
    float tmax = -3.0e38f;
    if (fullTile) {
#pragma unroll
      for (int f = 0; f < 4; ++f) {
#pragma unroll
        for (int i = 0; i < 4; ++i) {
          float s = S4[f][i] * 0.125f;
          S4[f][i] = s;
          tmax = fmaxf(tmax, s);
        }
      }
    } else {
#pragma unroll
      for (int f = 0; f < 4; ++f) {
#pragma unroll
        for (int i = 0; i < 4; ++i) {
          const int key = tbase + f * 16 + lg * 4 + i;
          bool valid;
          if (isC) valid = (key <= LC - 1) && (p >= key * 4 + 7);
          else     valid = (p >= key) && (p - key < WINDOW);
          float s = valid ? S4[f][i] * 0.125f : -3.0e38f;
          S4[f][i] = s;
          tmax = fmaxf(tmax, s);
        }
      }
    }
    tmax = fmaxf(tmax, __shfl_xor(tmax, 16));
    tmax = fmaxf(tmax, __shfl_xor(tmax, 32));

    // ---- exact defer-max: rescale only if any row max grew ----
    if (__any(tmax > mrow)) {
      float mn = fmaxf(mrow, tmax);
      float r = __expf(mrow - mn);
      mrow = mn;
      lrow *= r;
      float rb[4];
#pragma unroll
      for (int i = 0; i < 4; ++i) rb[i] = __shfl(r, lg * 4 + i);
#pragma unroll
      for (int f = 0; f < 4; ++f) {
#pragma unroll
        for (int i = 0; i < 4; ++i) Oacc[f][i] *= rb[i];
      }
    }

    // ---- P = exp(S - m); packed b64 writes; in-lane sum ----
    float lsum = 0.f;
#pragma unroll
    for (int f = 0; f < 4; ++f) {
      float e0 = (S4[f][0] > -1.0e38f) ? __expf(S4[f][0] - mrow) : 0.f;
      float e1 = (S4[f][1] > -1.0e38f) ? __expf(S4[f][1] - mrow) : 0.f;
      float e2 = (S4[f][2] > -1.0e38f) ? __expf(S4[f][2] - mrow) : 0.f;
      float e3 = (S4[f][3] > -1.0e38f) ? __expf(S4[f][3] - mrow) : 0.f;
      lsum += (e0 + e1) + (e2 + e3);
      uint2 pk;
      pk.x = (unsigned)f2bf(e0) | ((unsigned)f2bf(e1) << 16);
      pk.y = (unsigned)f2bf(e2) | ((unsigned)f2bf(e3) << 16);
      *(uint2*)&Pl[w][lr][f * 16 + lg * 4] = pk;
    }
    lsum += __shfl_xor(lsum, 16);
    lsum += __shfl_xor(lsum, 32);
    lrow += lsum;
    asm volatile("s_waitcnt lgkmcnt(0)" ::: "memory");

    // ---- PV: O[q=lg*4+i][d=f*16+lr] ----
    __builtin_amdgcn_s_setprio(1);
#pragma unroll
    for (int c = 0; c < 2; ++c) {
      short8 Pa = *(const short8*)&Pl[w][lr][c * 32 + lg * 8];
#pragma unroll
      for (int f = 0; f < 4; ++f) {
        short8 Vf = *(const short8*)&Vt[bsel][f * 16 + lr][c * 32 + lg * 8];
        Oacc[f] = __builtin_amdgcn_mfma_f32_16x16x32_bf16(Pa, Vf, Oacc[f], 0, 0, 0);
      }
    }
    __builtin_amdgcn_s_setprio(0);
  }

  // ---- sink + normalize (per-lane q=lr), broadcast to i-domain, write ----
  const float snk = sink[h];
  float ms = fmaxf(mrow, snk);
  float sc = __expf(mrow - ms);
  float li = lrow * sc + __expf(snk - ms);
  float osc = sc / li;
  float ob4[4];
#pragma unroll
  for (int i = 0; i < 4; ++i) ob4[i] = __shfl(osc, lg * 4 + i);
#pragma unroll
  for (int f = 0; f < 4; ++f) {
#pragma unroll
    for (int i = 0; i < 4; ++i) {
      size_t row = (size_t)(b * LSEQ + q0 + w * 16 + lg * 4 + i);
      ob[row * DMODEL + hoff + f * 16 + lr] = f2bf(Oacc[f][i] * ob4[i]);
    }
  }
}

// ---------------------------------------------------------------------------
// Launch
// ---------------------------------------------------------------------------
extern "C" void kernel_launch(void* const* d_in, const int* in_sizes, int n_in,
                              void* d_out, int out_size, void* d_ws, size_t ws_size,
                              hipStream_t stream) {
  const float* x    = (const float*)d_in[0];
  const float* wq   = (const float*)d_in[1];
  const float* wk   = (const float*)d_in[2];
  const float* wv   = (const float*)d_in[3];
  const float* wo   = (const float*)d_in[4];
  const float* wkc  = (const float*)d_in[5];
  const float* wvc  = (const float*)d_in[6];
  const float* gate = (const float*)d_in[7];
  const float* sink = (const float*)d_in[8];
  float* out = (float*)d_out;

  const int BL  = BATCH * LSEQ;   // 4096
  const int BLC = BATCH * LC;     // 1022
  const int NX  = BATCH * LSEQ * DMODEL;   // 2097152
  const int NW  = DMODEL * DMODEL;         // 262144

  char* wp = (char*)d_ws;
  auto carve = [&](size_t bytes) {
    char* r = wp;
    wp += (bytes + 255) & ~(size_t)255;
    return r;
  };
  unsigned short* qbuf = (unsigned short*)carve((size_t)BL * DMODEL * 2);
  unsigned short* kbuf = (unsigned short*)carve((size_t)BL * DMODEL * 2);
  unsigned short* vbuf = (unsigned short*)carve((size_t)BL * DMODEL * 2);
  unsigned short* kcb  = (unsigned short*)carve((size_t)BLC * DMODEL * 2);
  unsigned short* vcb  = (unsigned short*)carve((size_t)BLC * DMODEL * 2);
  unsigned short* xb   = (unsigned short*)carve((size_t)NX * 2);
  unsigned short* xcb  = (unsigned short*)carve((size_t)BLC * DMODEL * 2);
  unsigned short* ob   = (unsigned short*)carve((size_t)BL * DMODEL * 2);
  unsigned short* wqkvb = (unsigned short*)carve((size_t)NW * 3 * 2);
  unsigned short* wkvcb = (unsigned short*)carve((size_t)NW * 2 * 2);
  unsigned short* wob   = (unsigned short*)carve((size_t)NW * 2);
  float2* cstab = (float2*)carve((size_t)2048 * 32 * sizeof(float2));

  // 1) conversions + xc + cos/sin table
  conv_all<<<4351, 256, 0, stream>>>(x, wq, wk, wv, wkc, wvc, wo, gate,
                                     xb, wqkvb, wkvcb, wob, xcb, cstab);

  // 2) all projections + fused RoPE (2-phase pipelined, 32x32 MFMA)
  proj_gemm<<<448, 256, 0, stream>>>(xb, xcb, wqkvb, wkvcb, cstab,
                                     qbuf, kbuf, vbuf, kcb, vcb);

  // 3) attention (v8: mask fast paths)
  attn_kernel<<<BATCH * NHEADS * (LSEQ / 64), 256, 0, stream>>>(
      qbuf, kbuf, vbuf, kcb, vcb, sink, ob);

  // 4) output projection (2-phase pipelined, 32x32 MFMA)
  wo_gemm<<<dim3(BL / 128, DMODEL / 64), 256, 0, stream>>>(ob, wob, out);
}

// Round 13
// 56.421 us; speedup vs baseline: 1.0185x; 1.0185x over previous
//
#include <hip/hip_runtime.h>
#include <hip/hip_bf16.h>
#include <cmath>

#define BATCH 2
#define LSEQ 2048
#define DMODEL 512
#define NHEADS 8
#define HD 64
#define RATIO 8
#define STRIDE 4
#define WINDOW 128
#define LC 511   // (2048-8)/4 + 1

typedef short short8 __attribute__((ext_vector_type(8)));
typedef float floatx4 __attribute__((ext_vector_type(4)));

__device__ inline unsigned short f2bf(float f) {
  unsigned u = __float_as_uint(f);
  u += 0x7FFFu + ((u >> 16) & 1u);
  return (unsigned short)(u >> 16);
}

// async global->LDS 16B (dwordx4). LDS dest is wave-uniform base + lane*16.
__device__ inline void gld_lds16(const unsigned short* g, short* l) {
  __builtin_amdgcn_global_load_lds(
      (const __attribute__((address_space(1))) unsigned int*)g,
      (__attribute__((address_space(3))) unsigned int*)l, 16, 0, 0);
}

// ---------------------------------------------------------------------------
// Fused elementwise pass:
//   [0, 524288)           : x -> xb (bf16)
//   [524288, 917504)      : 6 weights -> wqkvb/wkvcb/wob (bf16)
//   [917504, 1048320)     : xc build (fp32 x -> bf16 xcb)
//   [1048320, 1113856)    : RoPE cos/sin table (float2 cstab[2048*32])
// ---------------------------------------------------------------------------
__global__ void conv_all(const float* __restrict__ x,
                         const float* __restrict__ w0, const float* __restrict__ w1,
                         const float* __restrict__ w2, const float* __restrict__ w3,
                         const float* __restrict__ w4, const float* __restrict__ w5,
                         const float* __restrict__ gate,
                         unsigned short* __restrict__ xb,
                         unsigned short* __restrict__ wqkvb,
                         unsigned short* __restrict__ wkvcb,
                         unsigned short* __restrict__ wob,
                         unsigned short* __restrict__ xcb,
                         float2* __restrict__ cstab) {
  int idx = blockIdx.x * blockDim.x + threadIdx.x;
  if (idx < 917504) {
    const float* src;
    unsigned short* dst;
    int off;
    if (idx < 524288) {
      src = x; dst = xb; off = idx;
    } else {
      int r = idx - 524288;
      int wi = r >> 16;
      off = r & 65535;
      switch (wi) {
        case 0: src = w0; dst = wqkvb; break;
        case 1: src = w1; dst = wqkvb + 4 * 65536; break;
        case 2: src = w2; dst = wqkvb + 8 * 65536; break;
        case 3: src = w3; dst = wkvcb; break;
        case 4: src = w4; dst = wkvcb + 4 * 65536; break;
        default: src = w5; dst = wob; break;
      }
    }
    float4 v = ((const float4*)src)[off];
    ushort4 o;
    o.x = f2bf(v.x); o.y = f2bf(v.y); o.z = f2bf(v.z); o.w = f2bf(v.w);
    ((ushort4*)dst)[off] = o;
  } else if (idx < 1048320) {
    int r = idx - 917504;           // [0, 130816) = 1022 * 128
    int d4 = r & 127;
    int t = r >> 7;
    int w = t % LC;
    int b = t / LC;
    float g[8];
    float m = -1e30f;
#pragma unroll
    for (int i = 0; i < 8; ++i) { g[i] = gate[i]; m = fmaxf(m, g[i]); }
    float ssum = 0.f;
#pragma unroll
    for (int i = 0; i < 8; ++i) { g[i] = __expf(g[i] - m); ssum += g[i]; }
    float inv = 1.f / ssum;
    const float* xb4 = x + ((size_t)(b * LSEQ + w * STRIDE)) * DMODEL + d4 * 4;
    float4 acc = make_float4(0.f, 0.f, 0.f, 0.f);
#pragma unroll
    for (int i = 0; i < 8; ++i) {
      float4 v = *(const float4*)(xb4 + (size_t)i * DMODEL);
      acc.x += g[i] * v.x; acc.y += g[i] * v.y;
      acc.z += g[i] * v.z; acc.w += g[i] * v.w;
    }
    ushort4 o;
    o.x = f2bf(acc.x * inv); o.y = f2bf(acc.y * inv);
    o.z = f2bf(acc.z * inv); o.w = f2bf(acc.w * inv);
    ((ushort4*)xcb)[(size_t)(b * LC + w) * 128 + d4] = o;
  } else {
    int e = idx - 1048320;          // [0, 65536) = 2048 * 32
    int p = e >> 5, j = e & 31;
    float inv_freq = __expf(-(float)j * (9.210340371976184f / 32.f));
    float s, c;
    sincosf((float)p * inv_freq, &s, &c);
    cstab[e] = make_float2(c, s);
  }
}

// ---------------------------------------------------------------------------
// Fused projection GEMM (448 blocks, 128x128 tiles, BK=64). 2-phase pipeline:
// stage(k+1) issued BEFORE compute(k) into the other LDS buffer; single
// __syncthreads per step (its implicit vmcnt(0) drain covers the gld_lds).
// bid<384: QKV (RoPE fused); bid>=384: KCVC (row-clamped A).
// ---------------------------------------------------------------------------
__global__ __launch_bounds__(256) void proj_gemm(
    const unsigned short* __restrict__ xb, const unsigned short* __restrict__ xcb,
    const unsigned short* __restrict__ wqkvb, const unsigned short* __restrict__ wkvcb,
    const float2* __restrict__ cstab,
    unsigned short* __restrict__ qbuf, unsigned short* __restrict__ kbuf,
    unsigned short* __restrict__ vbuf, unsigned short* __restrict__ kcb,
    unsigned short* __restrict__ vcb) {
  __shared__ short As[2][128 * 64];
  __shared__ short Bs[2][128 * 64];
  const int tid = threadIdx.x;
  const int w = tid >> 6, l = tid & 63;
  const int lr = l & 15, lg = l >> 4;

  const int bid = blockIdx.x;
  const bool qkv = (bid < 384);
  const unsigned short* Ap;
  const unsigned short* Bp;
  int bm, bn, Am1;
  if (qkv) {
    Ap = xb; Bp = wqkvb; bm = (bid & 31) * 128; bn = (bid >> 5) * 128; Am1 = 4095;
  } else {
    int r = bid - 384;
    Ap = xcb; Bp = wkvcb; bm = (r & 7) * 128; bn = (r >> 3) * 128; Am1 = 1021;
  }
  const int wm = (w >> 1) * 64, wn = (w & 1) * 64;

  floatx4 acc[4][4];
#pragma unroll
  for (int i = 0; i < 4; ++i)
#pragma unroll
    for (int j = 0; j < 4; ++j) acc[i][j] = 0.f;

  const int trow = tid >> 3;
  const int cs = (tid & 7) ^ (trow & 7);
  size_t aoffs[4];
#pragma unroll
  for (int i = 0; i < 4; ++i) {
    int ar = bm + trow + i * 32;
    if (ar > Am1) ar = Am1;
    aoffs[i] = (size_t)ar * DMODEL + cs * 8;
  }
  const size_t boff = (size_t)(bn + trow) * DMODEL + cs * 8;
  const int ldsbase = (tid & 192) * 8;

  auto stage = [&](int ks, int buf) {
    const int k0 = ks * 64;
#pragma unroll
    for (int i = 0; i < 4; ++i) {
      gld_lds16(Ap + aoffs[i] + k0, &As[buf][i * 2048 + ldsbase]);
      gld_lds16(Bp + boff + (size_t)i * 32 * DMODEL + k0, &Bs[buf][i * 2048 + ldsbase]);
    }
  };

  stage(0, 0);
  __syncthreads();
  for (int ks = 0; ks < 8; ++ks) {
    const int cur = ks & 1;
    if (ks < 7) stage(ks + 1, cur ^ 1);
#pragma unroll
    for (int kk = 0; kk < 2; ++kk) {
      const int kc16 = kk * 4 + lg;
      short8 a[4], bf[4];
#pragma unroll
      for (int mi = 0; mi < 4; ++mi) {
        int r = wm + mi * 16 + lr;
        a[mi] = *(const short8*)&As[cur][r * 64 + ((kc16 ^ (r & 7)) * 8)];
      }
#pragma unroll
      for (int nj = 0; nj < 4; ++nj) {
        int r = wn + nj * 16 + lr;
        bf[nj] = *(const short8*)&Bs[cur][r * 64 + ((kc16 ^ (r & 7)) * 8)];
      }
#pragma unroll
      for (int mi = 0; mi < 4; ++mi)
#pragma unroll
        for (int nj = 0; nj < 4; ++nj)
          acc[mi][nj] = __builtin_amdgcn_mfma_f32_16x16x32_bf16(
              a[mi], bf[nj], acc[mi][nj], 0, 0, 0);
    }
    __syncthreads();
  }

  if (qkv) {
    if (bn < 1024) {
      unsigned short* dst = (bn < 512) ? qbuf : kbuf;
      const int cbase = (bn + wn) & 511;
#pragma unroll
      for (int mi = 0; mi < 4; ++mi) {
#pragma unroll
        for (int i = 0; i < 4; ++i) {
          int row = bm + wm + mi * 16 + lg * 4 + i;
          int p = row & 2047;
#pragma unroll
          for (int nj = 0; nj < 2; ++nj) {
            float2 cssin = cstab[p * 32 + nj * 16 + lr];
            float a = acc[mi][nj][i], b2 = acc[mi][nj + 2][i];
            int cc = cbase + nj * 16 + lr;
            dst[(size_t)row * 512 + cc] = f2bf(a * cssin.x - b2 * cssin.y);
            dst[(size_t)row * 512 + cc + 32] = f2bf(a * cssin.y + b2 * cssin.x);
          }
        }
      }
    } else {
#pragma unroll
      for (int mi = 0; mi < 4; ++mi) {
#pragma unroll
        for (int i = 0; i < 4; ++i) {
          int row = bm + wm + mi * 16 + lg * 4 + i;
#pragma unroll
          for (int nj = 0; nj < 4; ++nj) {
            int col = bn + wn + nj * 16 + lr - 1024;
            vbuf[(size_t)row * 512 + col] = f2bf(acc[mi][nj][i]);
          }
        }
      }
    }
  } else {
    unsigned short* dst = ((bn + wn) < 512) ? kcb : vcb;
    const int cbase = (bn + wn) & 511;
#pragma unroll
    for (int mi = 0; mi < 4; ++mi) {
#pragma unroll
      for (int i = 0; i < 4; ++i) {
        int row = bm + wm + mi * 16 + lg * 4 + i;
        if (row < 1022) {
#pragma unroll
          for (int nj = 0; nj < 4; ++nj)
            dst[(size_t)row * 512 + cbase + nj * 16 + lr] = f2bf(acc[mi][nj][i]);
        }
      }
    }
  }
}

// ---------------------------------------------------------------------------
// Output projection: C[4096,512] = ob x wob^T, fp32 out. 128x64 tiles,
// 2-phase pipelined staging.
// ---------------------------------------------------------------------------
__global__ __launch_bounds__(256) void wo_gemm(
    const unsigned short* __restrict__ A, const unsigned short* __restrict__ B,
    float* __restrict__ C) {
  __shared__ short As[2][128 * 64];
  __shared__ short Bs[2][64 * 64];
  const int tid = threadIdx.x;
  const int w = tid >> 6, l = tid & 63;
  const int lr = l & 15, lg = l >> 4;
  const int bm = blockIdx.x * 128, bn = blockIdx.y * 64;
  const int wm = (w >> 1) * 64, wn = (w & 1) * 32;

  floatx4 acc[4][2];
#pragma unroll
  for (int i = 0; i < 4; ++i)
#pragma unroll
    for (int j = 0; j < 2; ++j) acc[i][j] = 0.f;

  const int trow = tid >> 3;
  const int cs = (tid & 7) ^ (trow & 7);
  const size_t aoff = (size_t)(bm + trow) * DMODEL + cs * 8;
  const size_t boff = (size_t)(bn + trow) * DMODEL + cs * 8;
  const int ldsbase = (tid & 192) * 8;

  auto stage = [&](int ks, int buf) {
    const int k0 = ks * 64;
#pragma unroll
    for (int i = 0; i < 4; ++i)
      gld_lds16(A + aoff + (size_t)i * 32 * DMODEL + k0, &As[buf][i * 2048 + ldsbase]);
#pragma unroll
    for (int i = 0; i < 2; ++i)
      gld_lds16(B + boff + (size_t)i * 32 * DMODEL + k0, &Bs[buf][i * 2048 + ldsbase]);
  };

  stage(0, 0);
  __syncthreads();
  for (int ks = 0; ks < 8; ++ks) {
    const int cur = ks & 1;
    if (ks < 7) stage(ks + 1, cur ^ 1);
#pragma unroll
    for (int kk = 0; kk < 2; ++kk) {
      const int kc16 = kk * 4 + lg;
      short8 a[4], bf[2];
#pragma unroll
      for (int mi = 0; mi < 4; ++mi) {
        int r = wm + mi * 16 + lr;
        a[mi] = *(const short8*)&As[cur][r * 64 + ((kc16 ^ (r & 7)) * 8)];
      }
#pragma unroll
      for (int nj = 0; nj < 2; ++nj) {
        int r = wn + nj * 16 + lr;
        bf[nj] = *(const short8*)&Bs[cur][r * 64 + ((kc16 ^ (r & 7)) * 8)];
      }
#pragma unroll
      for (int mi = 0; mi < 4; ++mi)
#pragma unroll
        for (int nj = 0; nj < 2; ++nj)
          acc[mi][nj] = __builtin_amdgcn_mfma_f32_16x16x32_bf16(
              a[mi], bf[nj], acc[mi][nj], 0, 0, 0);
    }
    __syncthreads();
  }

#pragma unroll
  for (int mi = 0; mi < 4; ++mi) {
#pragma unroll
    for (int i = 0; i < 4; ++i) {
      int row = bm + wm + mi * 16 + lg * 4 + i;
#pragma unroll
      for (int nj = 0; nj < 2; ++nj)
        C[(size_t)row * 512 + bn + wn + nj * 16 + lr] = acc[mi][nj][i];
    }
  }
}

// ---------------------------------------------------------------------------
// Attention v9: v8 logic, occupancy raised to 3 blocks/CU (LDS 46080 B fits
// 3; launch_bounds(256,3) caps VGPR ~170 which the kernel's live state fits).
// ---------------------------------------------------------------------------
__global__ __launch_bounds__(256, 3) void attn_kernel(
    const unsigned short* __restrict__ qb, const unsigned short* __restrict__ kb,
    const unsigned short* __restrict__ vb, const unsigned short* __restrict__ kcb,
    const unsigned short* __restrict__ vcb, const float* __restrict__ sink,
    unsigned short* __restrict__ ob) {
  __shared__ short Ks[2][64][72];
  __shared__ short Vt[2][64][72];
  __shared__ short Pl[4][16][72];

  const int n = blockIdx.x;
  const int b = n >> 8;
  const int mm = n & 255;
  const int h = mm >> 5;
  int qt = mm & 31;
  if (b) qt = 31 - qt;
  const int q0 = qt * 64;
  const int tid = threadIdx.x;
  const int w = tid >> 6, l = tid & 63;
  const int lr = l & 15, lg = l >> 4;
  const int hoff = h * HD;

  short8 Qa0, Qa1;
  {
    const unsigned short* qrow =
        qb + ((size_t)(b * LSEQ + q0 + w * 16 + lr)) * DMODEL + hoff;
    Qa0 = *(const short8*)(qrow + lg * 8);
    Qa1 = *(const short8*)(qrow + 32 + lg * 8);
  }

  floatx4 Oacc[4];
#pragma unroll
  for (int f = 0; f < 4; ++f) Oacc[f] = 0.f;
  float mrow = -3.0e38f, lrow = 0.f;    // per-lane: q = q0 + w*16 + lr

  int ncm = q0 / 4 + 15;
  if (ncm > LC) ncm = LC;
  const int ntc = (ncm + 63) >> 6;
  const int w0 = (q0 > 127) ? (q0 - 127) : 0;
  const int ntw = (q0 + 64 - w0 + 63) >> 6;
  const int ntt = ntc + ntw;

  const int skey = tid >> 2, sd = (tid & 3) * 16;
  const int vkey = (tid & 31) * 2, vd = (tid >> 5) * 8;
  const int p = q0 + w * 16 + lr;       // lane-fixed query position
  const int pmin = q0 + w * 16;         // wave-uniform min query

  short8 kreg0, kreg1, vreg0, vreg1;

  auto load_tile = [&](int tt) {
    const bool isC = (tt < ntc);
    const int tbase = isC ? tt * 64 : (w0 + (tt - ntc) * 64);
    const unsigned short* Kp = isC ? kcb : kb;
    const unsigned short* Vp = isC ? vcb : vb;
    const int rmax = isC ? (LC - 1) : (LSEQ - 1);
    const size_t brow = isC ? (size_t)(b * LC) : (size_t)(b * LSEQ);
    int kr = tbase + skey;      if (kr > rmax) kr = rmax;
    int vr0 = tbase + vkey;     if (vr0 > rmax) vr0 = rmax;
    int vr1 = tbase + vkey + 1; if (vr1 > rmax) vr1 = rmax;
    const unsigned short* src = Kp + (brow + kr) * DMODEL + hoff + sd;
    kreg0 = *(const short8*)(src);
    kreg1 = *(const short8*)(src + 8);
    vreg0 = *(const short8*)(Vp + (brow + vr0) * DMODEL + hoff + vd);
    vreg1 = *(const short8*)(Vp + (brow + vr1) * DMODEL + hoff + vd);
  };
  auto store_tile = [&](int bsel) {
    *(short8*)&Ks[bsel][skey][sd] = kreg0;
    *(short8*)&Ks[bsel][skey][sd + 8] = kreg1;
#pragma unroll
    for (int j = 0; j < 8; ++j) {
      unsigned pk = (unsigned)(unsigned short)vreg0[j] |
                    ((unsigned)(unsigned short)vreg1[j] << 16);
      *(unsigned*)&Vt[bsel][vd + j][vkey] = pk;
    }
  };

  load_tile(0);

  for (int tt = 0; tt < ntt; ++tt) {
    const int bsel = tt & 1;
    store_tile(bsel);
    if (tt + 1 < ntt) load_tile(tt + 1);
    __syncthreads();

    const bool isC = (tt < ntc);
    const int tbase = isC ? tt * 64 : (w0 + (tt - ntc) * 64);

    // wave-uniform classification
    const bool deadTile = isC ? (tbase * 4 + 7 > pmin + 15)     // all keys future
                              : (tbase > pmin + 15);
    if (deadTile) continue;   // staging/barrier already done; skip compute
    const bool fullTile = isC
        ? ((tbase + 63) * 4 + 7 <= pmin) && (tbase + 63 <= LC - 1)
        : (tbase + 63 <= pmin) && (tbase >= pmin + 15 - (WINDOW - 1));

    // ---- S = K Q^T (swapped): lane q=lr fixed, keys = tbase+f*16+lg*4+i ----
    floatx4 S4[4];
    __builtin_amdgcn_s_setprio(1);
#pragma unroll
    for (int f = 0; f < 4; ++f) {
      floatx4 acc = 0.f;
      short8 kf0 = *(const short8*)&Ks[bsel][f * 16 + lr][lg * 8];
      short8 kf1 = *(const short8*)&Ks[bsel][f * 16 + lr][32 + lg * 8];
      acc = __builtin_amdgcn_mfma_f32_16x16x32_bf16(kf0, Qa0, acc, 0, 0, 0);
      acc = __builtin_amdgcn_mfma_f32_16x16x32_bf16(kf1, Qa1, acc, 0, 0, 0);
      S4[f] = acc;
    }
    __builtin_amdgcn_s_setprio(0);

    // ---- mask + scale; in-lane row max ----
    float tmax = -3.0e38f;
    if (fullTile) {
#pragma unroll
      for (int f = 0; f < 4; ++f) {
#pragma unroll
        for (int i = 0; i < 4; ++i) {
          float s = S4[f][i] * 0.125f;
          S4[f][i] = s;
          tmax = fmaxf(tmax, s);
        }
      }
    } else {
#pragma unroll
      for (int f = 0; f < 4; ++f) {
#pragma unroll
        for (int i = 0; i < 4; ++i) {
          const int key = tbase + f * 16 + lg * 4 + i;
          bool valid;
          if (isC) valid = (key <= LC - 1) && (p >= key * 4 + 7);
          else     valid = (p >= key) && (p - key < WINDOW);
          float s = valid ? S4[f][i] * 0.125f : -3.0e38f;
          S4[f][i] = s;
          tmax = fmaxf(tmax, s);
        }
      }
    }
    tmax = fmaxf(tmax, __shfl_xor(tmax, 16));
    tmax = fmaxf(tmax, __shfl_xor(tmax, 32));

    // ---- exact defer-max: rescale only if any row max grew ----
    if (__any(tmax > mrow)) {
      float mn = fmaxf(mrow, tmax);
      float r = __expf(mrow - mn);
      mrow = mn;
      lrow *= r;
      float rb[4];
#pragma unroll
      for (int i = 0; i < 4; ++i) rb[i] = __shfl(r, lg * 4 + i);
#pragma unroll
      for (int f = 0; f < 4; ++f) {
#pragma unroll
        for (int i = 0; i < 4; ++i) Oacc[f][i] *= rb[i];
      }
    }

    // ---- P = exp(S - m); packed b64 writes; in-lane sum ----
    float lsum = 0.f;
#pragma unroll
    for (int f = 0; f < 4; ++f) {
      float e0 = (S4[f][0] > -1.0e38f) ? __expf(S4[f][0] - mrow) : 0.f;
      float e1 = (S4[f][1] > -1.0e38f) ? __expf(S4[f][1] - mrow) : 0.f;
      float e2 = (S4[f][2] > -1.0e38f) ? __expf(S4[f][2] - mrow) : 0.f;
      float e3 = (S4[f][3] > -1.0e38f) ? __expf(S4[f][3] - mrow) : 0.f;
      lsum += (e0 + e1) + (e2 + e3);
      uint2 pk;
      pk.x = (unsigned)f2bf(e0) | ((unsigned)f2bf(e1) << 16);
      pk.y = (unsigned)f2bf(e2) | ((unsigned)f2bf(e3) << 16);
      *(uint2*)&Pl[w][lr][f * 16 + lg * 4] = pk;
    }
    lsum += __shfl_xor(lsum, 16);
    lsum += __shfl_xor(lsum, 32);
    lrow += lsum;
    asm volatile("s_waitcnt lgkmcnt(0)" ::: "memory");

    // ---- PV: O[q=lg*4+i][d=f*16+lr] ----
    __builtin_amdgcn_s_setprio(1);
#pragma unroll
    for (int c = 0; c < 2; ++c) {
      short8 Pa = *(const short8*)&Pl[w][lr][c * 32 + lg * 8];
#pragma unroll
      for (int f = 0; f < 4; ++f) {
        short8 Vf = *(const short8*)&Vt[bsel][f * 16 + lr][c * 32 + lg * 8];
        Oacc[f] = __builtin_amdgcn_mfma_f32_16x16x32_bf16(Pa, Vf, Oacc[f], 0, 0, 0);
      }
    }
    __builtin_amdgcn_s_setprio(0);
  }

  // ---- sink + normalize (per-lane q=lr), broadcast to i-domain, write ----
  const float snk = sink[h];
  float ms = fmaxf(mrow, snk);
  float sc = __expf(mrow - ms);
  float li = lrow * sc + __expf(snk - ms);
  float osc = sc / li;
  float ob4[4];
#pragma unroll
  for (int i = 0; i < 4; ++i) ob4[i] = __shfl(osc, lg * 4 + i);
#pragma unroll
  for (int f = 0; f < 4; ++f) {
#pragma unroll
    for (int i = 0; i < 4; ++i) {
      size_t row = (size_t)(b * LSEQ + q0 + w * 16 + lg * 4 + i);
      ob[row * DMODEL + hoff + f * 16 + lr] = f2bf(Oacc[f][i] * ob4[i]);
    }
  }
}

// ---------------------------------------------------------------------------
// Launch
// ---------------------------------------------------------------------------
extern "C" void kernel_launch(void* const* d_in, const int* in_sizes, int n_in,
                              void* d_out, int out_size, void* d_ws, size_t ws_size,
                              hipStream_t stream) {
  const float* x    = (const float*)d_in[0];
  const float* wq   = (const float*)d_in[1];
  const float* wk   = (const float*)d_in[2];
  const float* wv   = (const float*)d_in[3];
  const float* wo   = (const float*)d_in[4];
  const float* wkc  = (const float*)d_in[5];
  const float* wvc  = (const float*)d_in[6];
  const float* gate = (const float*)d_in[7];
  const float* sink = (const float*)d_in[8];
  float* out = (float*)d_out;

  const int BL  = BATCH * LSEQ;   // 4096
  const int BLC = BATCH * LC;     // 1022
  const int NX  = BATCH * LSEQ * DMODEL;   // 2097152
  const int NW  = DMODEL * DMODEL;         // 262144

  char* wp = (char*)d_ws;
  auto carve = [&](size_t bytes) {
    char* r = wp;
    wp += (bytes + 255) & ~(size_t)255;
    return r;
  };
  unsigned short* qbuf = (unsigned short*)carve((size_t)BL * DMODEL * 2);
  unsigned short* kbuf = (unsigned short*)carve((size_t)BL * DMODEL * 2);
  unsigned short* vbuf = (unsigned short*)carve((size_t)BL * DMODEL * 2);
  unsigned short* kcb  = (unsigned short*)carve((size_t)BLC * DMODEL * 2);
  unsigned short* vcb  = (unsigned short*)carve((size_t)BLC * DMODEL * 2);
  unsigned short* xb   = (unsigned short*)carve((size_t)NX * 2);
  unsigned short* xcb  = (unsigned short*)carve((size_t)BLC * DMODEL * 2);
  unsigned short* ob   = (unsigned short*)carve((size_t)BL * DMODEL * 2);
  unsigned short* wqkvb = (unsigned short*)carve((size_t)NW * 3 * 2);
  unsigned short* wkvcb = (unsigned short*)carve((size_t)NW * 2 * 2);
  unsigned short* wob   = (unsigned short*)carve((size_t)NW * 2);
  float2* cstab = (float2*)carve((size_t)2048 * 32 * sizeof(float2));

  // 1) conversions + xc + cos/sin table
  conv_all<<<4351, 256, 0, stream>>>(x, wq, wk, wv, wkc, wvc, wo, gate,
                                     xb, wqkvb, wkvcb, wob, xcb, cstab);

  // 2) all projections + fused RoPE (2-phase pipelined)
  proj_gemm<<<448, 256, 0, stream>>>(xb, xcb, wqkvb, wkvcb, cstab,
                                     qbuf, kbuf, vbuf, kcb, vcb);

  // 3) attention (v9: 3 blocks/CU)
  attn_kernel<<<BATCH * NHEADS * (LSEQ / 64), 256, 0, stream>>>(
      qbuf, kbuf, vbuf, kcb, vcb, sink, ob);

  // 4) output projection (2-phase pipelined)
  wo_gemm<<<dim3(BL / 128, DMODEL / 64), 256, 0, stream>>>(ob, wob, out);
}

// Round 14
// 53.444 us; speedup vs baseline: 1.0753x; 1.0557x over previous
//
#include <hip/hip_runtime.h>
#include <hip/hip_bf16.h>
#include <cmath>

#define BATCH 2
#define LSEQ 2048
#define DMODEL 512
#define NHEADS 8
#define HD 64
#define RATIO 8
#define STRIDE 4
#define WINDOW 128
#define LC 511   // (2048-8)/4 + 1

typedef short short8 __attribute__((ext_vector_type(8)));
typedef float floatx4 __attribute__((ext_vector_type(4)));

__device__ inline unsigned short f2bf(float f) {
  unsigned u = __float_as_uint(f);
  u += 0x7FFFu + ((u >> 16) & 1u);
  return (unsigned short)(u >> 16);
}

// async global->LDS 16B (dwordx4). LDS dest is wave-uniform base + lane*16.
__device__ inline void gld_lds16(const unsigned short* g, short* l) {
  __builtin_amdgcn_global_load_lds(
      (const __attribute__((address_space(1))) unsigned int*)g,
      (__attribute__((address_space(3))) unsigned int*)l, 16, 0, 0);
}

// ---------------------------------------------------------------------------
// Fused elementwise pass:
//   [0, 524288)           : x -> xb (bf16)
//   [524288, 917504)      : 6 weights -> wqkvb/wkvcb/wob (bf16)
//   [917504, 1048320)     : xc build (fp32 x -> bf16 xcb)
//   [1048320, 1113856)    : RoPE cos/sin table (float2 cstab[2048*32])
// ---------------------------------------------------------------------------
__global__ void conv_all(const float* __restrict__ x,
                         const float* __restrict__ w0, const float* __restrict__ w1,
                         const float* __restrict__ w2, const float* __restrict__ w3,
                         const float* __restrict__ w4, const float* __restrict__ w5,
                         const float* __restrict__ gate,
                         unsigned short* __restrict__ xb,
                         unsigned short* __restrict__ wqkvb,
                         unsigned short* __restrict__ wkvcb,
                         unsigned short* __restrict__ wob,
                         unsigned short* __restrict__ xcb,
                         float2* __restrict__ cstab) {
  int idx = blockIdx.x * blockDim.x + threadIdx.x;
  if (idx < 917504) {
    const float* src;
    unsigned short* dst;
    int off;
    if (idx < 524288) {
      src = x; dst = xb; off = idx;
    } else {
      int r = idx - 524288;
      int wi = r >> 16;
      off = r & 65535;
      switch (wi) {
        case 0: src = w0; dst = wqkvb; break;
        case 1: src = w1; dst = wqkvb + 4 * 65536; break;
        case 2: src = w2; dst = wqkvb + 8 * 65536; break;
        case 3: src = w3; dst = wkvcb; break;
        case 4: src = w4; dst = wkvcb + 4 * 65536; break;
        default: src = w5; dst = wob; break;
      }
    }
    float4 v = ((const float4*)src)[off];
    ushort4 o;
    o.x = f2bf(v.x); o.y = f2bf(v.y); o.z = f2bf(v.z); o.w = f2bf(v.w);
    ((ushort4*)dst)[off] = o;
  } else if (idx < 1048320) {
    int r = idx - 917504;           // [0, 130816) = 1022 * 128
    int d4 = r & 127;
    int t = r >> 7;
    int w = t % LC;
    int b = t / LC;
    float g[8];
    float m = -1e30f;
#pragma unroll
    for (int i = 0; i < 8; ++i) { g[i] = gate[i]; m = fmaxf(m, g[i]); }
    float ssum = 0.f;
#pragma unroll
    for (int i = 0; i < 8; ++i) { g[i] = __expf(g[i] - m); ssum += g[i]; }
    float inv = 1.f / ssum;
    const float* xb4 = x + ((size_t)(b * LSEQ + w * STRIDE)) * DMODEL + d4 * 4;
    float4 acc = make_float4(0.f, 0.f, 0.f, 0.f);
#pragma unroll
    for (int i = 0; i < 8; ++i) {
      float4 v = *(const float4*)(xb4 + (size_t)i * DMODEL);
      acc.x += g[i] * v.x; acc.y += g[i] * v.y;
      acc.z += g[i] * v.z; acc.w += g[i] * v.w;
    }
    ushort4 o;
    o.x = f2bf(acc.x * inv); o.y = f2bf(acc.y * inv);
    o.z = f2bf(acc.z * inv); o.w = f2bf(acc.w * inv);
    ((ushort4*)xcb)[(size_t)(b * LC + w) * 128 + d4] = o;
  } else {
    int e = idx - 1048320;          // [0, 65536) = 2048 * 32
    int p = e >> 5, j = e & 31;
    float inv_freq = __expf(-(float)j * (9.210340371976184f / 32.f));
    float s, c;
    sincosf((float)p * inv_freq, &s, &c);
    cstab[e] = make_float2(c, s);
  }
}

// ---------------------------------------------------------------------------
// Fused projection GEMM (448 blocks, 128x128 tiles, BK=64). Counted-vmcnt
// pipeline: stage(k+1) issued, then vmcnt(8) drains ONLY stage(k) (oldest 8),
// raw s_barrier, compute(k), second barrier before buf reuse. Next-stage
// loads stay in flight across the barrier (T4).
// bid<384: QKV (RoPE fused); bid>=384: KCVC (row-clamped A).
// ---------------------------------------------------------------------------
__global__ __launch_bounds__(256) void proj_gemm(
    const unsigned short* __restrict__ xb, const unsigned short* __restrict__ xcb,
    const unsigned short* __restrict__ wqkvb, const unsigned short* __restrict__ wkvcb,
    const float2* __restrict__ cstab,
    unsigned short* __restrict__ qbuf, unsigned short* __restrict__ kbuf,
    unsigned short* __restrict__ vbuf, unsigned short* __restrict__ kcb,
    unsigned short* __restrict__ vcb) {
  __shared__ short As[2][128 * 64];
  __shared__ short Bs[2][128 * 64];
  const int tid = threadIdx.x;
  const int w = tid >> 6, l = tid & 63;
  const int lr = l & 15, lg = l >> 4;

  const int bid = blockIdx.x;
  const bool qkv = (bid < 384);
  const unsigned short* Ap;
  const unsigned short* Bp;
  int bm, bn, Am1;
  if (qkv) {
    Ap = xb; Bp = wqkvb; bm = (bid & 31) * 128; bn = (bid >> 5) * 128; Am1 = 4095;
  } else {
    int r = bid - 384;
    Ap = xcb; Bp = wkvcb; bm = (r & 7) * 128; bn = (r >> 3) * 128; Am1 = 1021;
  }
  const int wm = (w >> 1) * 64, wn = (w & 1) * 64;

  floatx4 acc[4][4];
#pragma unroll
  for (int i = 0; i < 4; ++i)
#pragma unroll
    for (int j = 0; j < 4; ++j) acc[i][j] = 0.f;

  const int trow = tid >> 3;
  const int cs = (tid & 7) ^ (trow & 7);
  size_t aoffs[4];
#pragma unroll
  for (int i = 0; i < 4; ++i) {
    int ar = bm + trow + i * 32;
    if (ar > Am1) ar = Am1;
    aoffs[i] = (size_t)ar * DMODEL + cs * 8;
  }
  const size_t boff = (size_t)(bn + trow) * DMODEL + cs * 8;
  const int ldsbase = (tid & 192) * 8;

  auto stage = [&](int ks, int buf) {
    const int k0 = ks * 64;
#pragma unroll
    for (int i = 0; i < 4; ++i) {
      gld_lds16(Ap + aoffs[i] + k0, &As[buf][i * 2048 + ldsbase]);
      gld_lds16(Bp + boff + (size_t)i * 32 * DMODEL + k0, &Bs[buf][i * 2048 + ldsbase]);
    }
  };

  stage(0, 0);
  for (int ks = 0; ks < 8; ++ks) {
    const int cur = ks & 1;
    if (ks < 7) {
      stage(ks + 1, cur ^ 1);
      asm volatile("s_waitcnt vmcnt(8)" ::: "memory");   // stage(ks) landed
    } else {
      asm volatile("s_waitcnt vmcnt(0)" ::: "memory");
    }
    __builtin_amdgcn_s_barrier();
    asm volatile("" ::: "memory");
#pragma unroll
    for (int kk = 0; kk < 2; ++kk) {
      const int kc16 = kk * 4 + lg;
      short8 a[4], bf[4];
#pragma unroll
      for (int mi = 0; mi < 4; ++mi) {
        int r = wm + mi * 16 + lr;
        a[mi] = *(const short8*)&As[cur][r * 64 + ((kc16 ^ (r & 7)) * 8)];
      }
#pragma unroll
      for (int nj = 0; nj < 4; ++nj) {
        int r = wn + nj * 16 + lr;
        bf[nj] = *(const short8*)&Bs[cur][r * 64 + ((kc16 ^ (r & 7)) * 8)];
      }
#pragma unroll
      for (int mi = 0; mi < 4; ++mi)
#pragma unroll
        for (int nj = 0; nj < 4; ++nj)
          acc[mi][nj] = __builtin_amdgcn_mfma_f32_16x16x32_bf16(
              a[mi], bf[nj], acc[mi][nj], 0, 0, 0);
    }
    asm volatile("" ::: "memory");
    __builtin_amdgcn_s_barrier();    // readers done before buf[cur] is restaged
  }

  if (qkv) {
    if (bn < 1024) {
      unsigned short* dst = (bn < 512) ? qbuf : kbuf;
      const int cbase = (bn + wn) & 511;
#pragma unroll
      for (int mi = 0; mi < 4; ++mi) {
#pragma unroll
        for (int i = 0; i < 4; ++i) {
          int row = bm + wm + mi * 16 + lg * 4 + i;
          int p = row & 2047;
#pragma unroll
          for (int nj = 0; nj < 2; ++nj) {
            float2 cssin = cstab[p * 32 + nj * 16 + lr];
            float a = acc[mi][nj][i], b2 = acc[mi][nj + 2][i];
            int cc = cbase + nj * 16 + lr;
            dst[(size_t)row * 512 + cc] = f2bf(a * cssin.x - b2 * cssin.y);
            dst[(size_t)row * 512 + cc + 32] = f2bf(a * cssin.y + b2 * cssin.x);
          }
        }
      }
    } else {
#pragma unroll
      for (int mi = 0; mi < 4; ++mi) {
#pragma unroll
        for (int i = 0; i < 4; ++i) {
          int row = bm + wm + mi * 16 + lg * 4 + i;
#pragma unroll
          for (int nj = 0; nj < 4; ++nj) {
            int col = bn + wn + nj * 16 + lr - 1024;
            vbuf[(size_t)row * 512 + col] = f2bf(acc[mi][nj][i]);
          }
        }
      }
    }
  } else {
    unsigned short* dst = ((bn + wn) < 512) ? kcb : vcb;
    const int cbase = (bn + wn) & 511;
#pragma unroll
    for (int mi = 0; mi < 4; ++mi) {
#pragma unroll
      for (int i = 0; i < 4; ++i) {
        int row = bm + wm + mi * 16 + lg * 4 + i;
        if (row < 1022) {
#pragma unroll
          for (int nj = 0; nj < 4; ++nj)
            dst[(size_t)row * 512 + cbase + nj * 16 + lr] = f2bf(acc[mi][nj][i]);
        }
      }
    }
  }
}

// ---------------------------------------------------------------------------
// Output projection: C[4096,512] = ob x wob^T, fp32 out. 128x64 tiles,
// counted-vmcnt pipeline (6 loads/stage).
// ---------------------------------------------------------------------------
__global__ __launch_bounds__(256) void wo_gemm(
    const unsigned short* __restrict__ A, const unsigned short* __restrict__ B,
    float* __restrict__ C) {
  __shared__ short As[2][128 * 64];
  __shared__ short Bs[2][64 * 64];
  const int tid = threadIdx.x;
  const int w = tid >> 6, l = tid & 63;
  const int lr = l & 15, lg = l >> 4;
  const int bm = blockIdx.x * 128, bn = blockIdx.y * 64;
  const int wm = (w >> 1) * 64, wn = (w & 1) * 32;

  floatx4 acc[4][2];
#pragma unroll
  for (int i = 0; i < 4; ++i)
#pragma unroll
    for (int j = 0; j < 2; ++j) acc[i][j] = 0.f;

  const int trow = tid >> 3;
  const int cs = (tid & 7) ^ (trow & 7);
  const size_t aoff = (size_t)(bm + trow) * DMODEL + cs * 8;
  const size_t boff = (size_t)(bn + trow) * DMODEL + cs * 8;
  const int ldsbase = (tid & 192) * 8;

  auto stage = [&](int ks, int buf) {
    const int k0 = ks * 64;
#pragma unroll
    for (int i = 0; i < 4; ++i)
      gld_lds16(A + aoff + (size_t)i * 32 * DMODEL + k0, &As[buf][i * 2048 + ldsbase]);
#pragma unroll
    for (int i = 0; i < 2; ++i)
      gld_lds16(B + boff + (size_t)i * 32 * DMODEL + k0, &Bs[buf][i * 2048 + ldsbase]);
  };

  stage(0, 0);
  for (int ks = 0; ks < 8; ++ks) {
    const int cur = ks & 1;
    if (ks < 7) {
      stage(ks + 1, cur ^ 1);
      asm volatile("s_waitcnt vmcnt(6)" ::: "memory");   // stage(ks) landed
    } else {
      asm volatile("s_waitcnt vmcnt(0)" ::: "memory");
    }
    __builtin_amdgcn_s_barrier();
    asm volatile("" ::: "memory");
#pragma unroll
    for (int kk = 0; kk < 2; ++kk) {
      const int kc16 = kk * 4 + lg;
      short8 a[4], bf[2];
#pragma unroll
      for (int mi = 0; mi < 4; ++mi) {
        int r = wm + mi * 16 + lr;
        a[mi] = *(const short8*)&As[cur][r * 64 + ((kc16 ^ (r & 7)) * 8)];
      }
#pragma unroll
      for (int nj = 0; nj < 2; ++nj) {
        int r = wn + nj * 16 + lr;
        bf[nj] = *(const short8*)&Bs[cur][r * 64 + ((kc16 ^ (r & 7)) * 8)];
      }
#pragma unroll
      for (int mi = 0; mi < 4; ++mi)
#pragma unroll
        for (int nj = 0; nj < 2; ++nj)
          acc[mi][nj] = __builtin_amdgcn_mfma_f32_16x16x32_bf16(
              a[mi], bf[nj], acc[mi][nj], 0, 0, 0);
    }
    asm volatile("" ::: "memory");
    __builtin_amdgcn_s_barrier();
  }

#pragma unroll
  for (int mi = 0; mi < 4; ++mi) {
#pragma unroll
    for (int i = 0; i < 4; ++i) {
      int row = bm + wm + mi * 16 + lg * 4 + i;
#pragma unroll
      for (int nj = 0; nj < 2; ++nj)
        C[(size_t)row * 512 + bn + wn + nj * 16 + lr] = acc[mi][nj][i];
    }
  }
}

// ---------------------------------------------------------------------------
// Attention v8 (reverted to 2 blocks/CU; R13's occ-3 was null): swapped-QK
// in-lane softmax + wave-uniform mask fast paths + dbuf staging + setprio.
// ---------------------------------------------------------------------------
__global__ __launch_bounds__(256, 2) void attn_kernel(
    const unsigned short* __restrict__ qb, const unsigned short* __restrict__ kb,
    const unsigned short* __restrict__ vb, const unsigned short* __restrict__ kcb,
    const unsigned short* __restrict__ vcb, const float* __restrict__ sink,
    unsigned short* __restrict__ ob) {
  __shared__ short Ks[2][64][72];
  __shared__ short Vt[2][64][72];
  __shared__ short Pl[4][16][72];

  const int n = blockIdx.x;
  const int b = n >> 8;
  const int mm = n & 255;
  const int h = mm >> 5;
  int qt = mm & 31;
  if (b) qt = 31 - qt;
  const int q0 = qt * 64;
  const int tid = threadIdx.x;
  const int w = tid >> 6, l = tid & 63;
  const int lr = l & 15, lg = l >> 4;
  const int hoff = h * HD;

  short8 Qa0, Qa1;
  {
    const unsigned short* qrow =
        qb + ((size_t)(b * LSEQ + q0 + w * 16 + lr)) * DMODEL + hoff;
    Qa0 = *(const short8*)(qrow + lg * 8);
    Qa1 = *(const short8*)(qrow + 32 + lg * 8);
  }

  floatx4 Oacc[4];
#pragma unroll
  for (int f = 0; f < 4; ++f) Oacc[f] = 0.f;
  float mrow = -3.0e38f, lrow = 0.f;    // per-lane: q = q0 + w*16 + lr

  int ncm = q0 / 4 + 15;
  if (ncm > LC) ncm = LC;
  const int ntc = (ncm + 63) >> 6;
  const int w0 = (q0 > 127) ? (q0 - 127) : 0;
  const int ntw = (q0 + 64 - w0 + 63) >> 6;
  const int ntt = ntc + ntw;

  const int skey = tid >> 2, sd = (tid & 3) * 16;
  const int vkey = (tid & 31) * 2, vd = (tid >> 5) * 8;
  const int p = q0 + w * 16 + lr;       // lane-fixed query position
  const int pmin = q0 + w * 16;         // wave-uniform min query

  short8 kreg0, kreg1, vreg0, vreg1;

  auto load_tile = [&](int tt) {
    const bool isC = (tt < ntc);
    const int tbase = isC ? tt * 64 : (w0 + (tt - ntc) * 64);
    const unsigned short* Kp = isC ? kcb : kb;
    const unsigned short* Vp = isC ? vcb : vb;
    const int rmax = isC ? (LC - 1) : (LSEQ - 1);
    const size_t brow = isC ? (size_t)(b * LC) : (size_t)(b * LSEQ);
    int kr = tbase + skey;      if (kr > rmax) kr = rmax;
    int vr0 = tbase + vkey;     if (vr0 > rmax) vr0 = rmax;
    int vr1 = tbase + vkey + 1; if (vr1 > rmax) vr1 = rmax;
    const unsigned short* src = Kp + (brow + kr) * DMODEL + hoff + sd;
    kreg0 = *(const short8*)(src);
    kreg1 = *(const short8*)(src + 8);
    vreg0 = *(const short8*)(Vp + (brow + vr0) * DMODEL + hoff + vd);
    vreg1 = *(const short8*)(Vp + (brow + vr1) * DMODEL + hoff + vd);
  };
  auto store_tile = [&](int bsel) {
    *(short8*)&Ks[bsel][skey][sd] = kreg0;
    *(short8*)&Ks[bsel][skey][sd + 8] = kreg1;
#pragma unroll
    for (int j = 0; j < 8; ++j) {
      unsigned pk = (unsigned)(unsigned short)vreg0[j] |
                    ((unsigned)(unsigned short)vreg1[j] << 16);
      *(unsigned*)&Vt[bsel][vd + j][vkey] = pk;
    }
  };

  load_tile(0);

  for (int tt = 0; tt < ntt; ++tt) {
    const int bsel = tt & 1;
    store_tile(bsel);
    if (tt + 1 < ntt) load_tile(tt + 1);
    __syncthreads();

    const bool isC = (tt < ntc);
    const int tbase = isC ? tt * 64 : (w0 + (tt - ntc) * 64);

    // wave-uniform classification
    const bool deadTile = isC ? (tbase * 4 + 7 > pmin + 15)     // all keys future
                              : (tbase > pmin + 15);
    if (deadTile) continue;   // staging/barrier already done; skip compute
    const bool fullTile = isC
        ? ((tbase + 63) * 4 + 7 <= pmin) && (tbase + 63 <= LC - 1)
        : (tbase + 63 <= pmin) && (tbase >= pmin + 15 - (WINDOW - 1));

    // ---- S = K Q^T (swapped): lane q=lr fixed, keys = tbase+f*16+lg*4+i ----
    floatx4 S4[4];
    __builtin_amdgcn_s_setprio(1);
#pragma unroll
    for (int f = 0; f < 4; ++f) {
      floatx4 acc = 0.f;
      short8 kf0 = *(const short8*)&Ks[bsel][f * 16 + lr][lg * 8];
      short8 kf1 = *(const short8*)&Ks[bsel][f * 16 + lr][32 + lg * 8];
      acc = __builtin_amdgcn_mfma_f32_16x16x32_bf16(kf0, Qa0, acc, 0, 0, 0);
      acc = __builtin_amdgcn_mfma_f32_16x16x32_bf16(kf1, Qa1, acc, 0, 0, 0);
      S4[f] = acc;
    }
    __builtin_amdgcn_s_setprio(0);

    // ---- mask + scale; in-lane row max ----
    float tmax = -3.0e38f;
    if (fullTile) {
#pragma unroll
      for (int f = 0; f < 4; ++f) {
#pragma unroll
        for (int i = 0; i < 4; ++i) {
          float s = S4[f][i] * 0.125f;
          S4[f][i] = s;
          tmax = fmaxf(tmax, s);
        }
      }
    } else {
#pragma unroll
      for (int f = 0; f < 4; ++f) {
#pragma unroll
        for (int i = 0; i < 4; ++i) {
          const int key = tbase + f * 16 + lg * 4 + i;
          bool valid;
          if (isC) valid = (key <= LC - 1) && (p >= key * 4 + 7);
          else     valid = (p >= key) && (p - key < WINDOW);
          float s = valid ? S4[f][i] * 0.125f : -3.0e38f;
          S4[f][i] = s;
          tmax = fmaxf(tmax, s);
        }
      }
    }
    tmax = fmaxf(tmax, __shfl_xor(tmax, 16));
    tmax = fmaxf(tmax, __shfl_xor(tmax, 32));

    // ---- exact defer-max: rescale only if any row max grew ----
    if (__any(tmax > mrow)) {
      float mn = fmaxf(mrow, tmax);
      float r = __expf(mrow - mn);
      mrow = mn;
      lrow *= r;
      float rb[4];
#pragma unroll
      for (int i = 0; i < 4; ++i) rb[i] = __shfl(r, lg * 4 + i);
#pragma unroll
      for (int f = 0; f < 4; ++f) {
#pragma unroll
        for (int i = 0; i < 4; ++i) Oacc[f][i] *= rb[i];
      }
    }

    // ---- P = exp(S - m); packed b64 writes; in-lane sum ----
    float lsum = 0.f;
#pragma unroll
    for (int f = 0; f < 4; ++f) {
      float e0 = (S4[f][0] > -1.0e38f) ? __expf(S4[f][0] - mrow) : 0.f;
      float e1 = (S4[f][1] > -1.0e38f) ? __expf(S4[f][1] - mrow) : 0.f;
      float e2 = (S4[f][2] > -1.0e38f) ? __expf(S4[f][2] - mrow) : 0.f;
      float e3 = (S4[f][3] > -1.0e38f) ? __expf(S4[f][3] - mrow) : 0.f;
      lsum += (e0 + e1) + (e2 + e3);
      uint2 pk;
      pk.x = (unsigned)f2bf(e0) | ((unsigned)f2bf(e1) << 16);
      pk.y = (unsigned)f2bf(e2) | ((unsigned)f2bf(e3) << 16);
      *(uint2*)&Pl[w][lr][f * 16 + lg * 4] = pk;
    }
    lsum += __shfl_xor(lsum, 16);
    lsum += __shfl_xor(lsum, 32);
    lrow += lsum;
    asm volatile("s_waitcnt lgkmcnt(0)" ::: "memory");

    // ---- PV: O[q=lg*4+i][d=f*16+lr] ----
    __builtin_amdgcn_s_setprio(1);
#pragma unroll
    for (int c = 0; c < 2; ++c) {
      short8 Pa = *(const short8*)&Pl[w][lr][c * 32 + lg * 8];
#pragma unroll
      for (int f = 0; f < 4; ++f) {
        short8 Vf = *(const short8*)&Vt[bsel][f * 16 + lr][c * 32 + lg * 8];
        Oacc[f] = __builtin_amdgcn_mfma_f32_16x16x32_bf16(Pa, Vf, Oacc[f], 0, 0, 0);
      }
    }
    __builtin_amdgcn_s_setprio(0);
  }

  // ---- sink + normalize (per-lane q=lr), broadcast to i-domain, write ----
  const float snk = sink[h];
  float ms = fmaxf(mrow, snk);
  float sc = __expf(mrow - ms);
  float li = lrow * sc + __expf(snk - ms);
  float osc = sc / li;
  float ob4[4];
#pragma unroll
  for (int i = 0; i < 4; ++i) ob4[i] = __shfl(osc, lg * 4 + i);
#pragma unroll
  for (int f = 0; f < 4; ++f) {
#pragma unroll
    for (int i = 0; i < 4; ++i) {
      size_t row = (size_t)(b * LSEQ + q0 + w * 16 + lg * 4 + i);
      ob[row * DMODEL + hoff + f * 16 + lr] = f2bf(Oacc[f][i] * ob4[i]);
    }
  }
}

// ---------------------------------------------------------------------------
// Launch
// ---------------------------------------------------------------------------
extern "C" void kernel_launch(void* const* d_in, const int* in_sizes, int n_in,
                              void* d_out, int out_size, void* d_ws, size_t ws_size,
                              hipStream_t stream) {
  const float* x    = (const float*)d_in[0];
  const float* wq   = (const float*)d_in[1];
  const float* wk   = (const float*)d_in[2];
  const float* wv   = (const float*)d_in[3];
  const float* wo   = (const float*)d_in[4];
  const float* wkc  = (const float*)d_in[5];
  const float* wvc  = (const float*)d_in[6];
  const float* gate = (const float*)d_in[7];
  const float* sink = (const float*)d_in[8];
  float* out = (float*)d_out;

  const int BL  = BATCH * LSEQ;   // 4096
  const int BLC = BATCH * LC;     // 1022
  const int NX  = BATCH * LSEQ * DMODEL;   // 2097152
  const int NW  = DMODEL * DMODEL;         // 262144

  char* wp = (char*)d_ws;
  auto carve = [&](size_t bytes) {
    char* r = wp;
    wp += (bytes + 255) & ~(size_t)255;
    return r;
  };
  unsigned short* qbuf = (unsigned short*)carve((size_t)BL * DMODEL * 2);
  unsigned short* kbuf = (unsigned short*)carve((size_t)BL * DMODEL * 2);
  unsigned short* vbuf = (unsigned short*)carve((size_t)BL * DMODEL * 2);
  unsigned short* kcb  = (unsigned short*)carve((size_t)BLC * DMODEL * 2);
  unsigned short* vcb  = (unsigned short*)carve((size_t)BLC * DMODEL * 2);
  unsigned short* xb   = (unsigned short*)carve((size_t)NX * 2);
  unsigned short* xcb  = (unsigned short*)carve((size_t)BLC * DMODEL * 2);
  unsigned short* ob   = (unsigned short*)carve((size_t)BL * DMODEL * 2);
  unsigned short* wqkvb = (unsigned short*)carve((size_t)NW * 3 * 2);
  unsigned short* wkvcb = (unsigned short*)carve((size_t)NW * 2 * 2);
  unsigned short* wob   = (unsigned short*)carve((size_t)NW * 2);
  float2* cstab = (float2*)carve((size_t)2048 * 32 * sizeof(float2));

  // 1) conversions + xc + cos/sin table
  conv_all<<<4351, 256, 0, stream>>>(x, wq, wk, wv, wkc, wvc, wo, gate,
                                     xb, wqkvb, wkvcb, wob, xcb, cstab);

  // 2) all projections + fused RoPE (counted-vmcnt pipeline)
  proj_gemm<<<448, 256, 0, stream>>>(xb, xcb, wqkvb, wkvcb, cstab,
                                     qbuf, kbuf, vbuf, kcb, vcb);

  // 3) attention (v8, 2 blocks/CU)
  attn_kernel<<<BATCH * NHEADS * (LSEQ / 64), 256, 0, stream>>>(
      qbuf, kbuf, vbuf, kcb, vcb, sink, ob);

  // 4) output projection (counted-vmcnt pipeline)
  wo_gemm<<<dim3(BL / 128, DMODEL / 64), 256, 0, stream>>>(ob, wob, out);
}